// Round 13
// baseline (277.015 us; speedup 1.0000x reference)
//
#include <hip/hip_runtime.h>
#include <cstddef>

// Problem constants
constexpr int Bn  = 512;
constexpr int Dd  = 960;
constexpr int RL  = 16;
constexpr int RD  = 32;
constexpr int LPp = 16;
constexpr int LHh = 384;
constexpr int DP  = 358;
constexpr int DH  = 154;
constexpr int CR  = 8;                     // rows per staged X chunk
constexpr int SLOTS = (CR * Dd) / 256;     // 30 slots of 1024 B (256 f32)

typedef float f32x4 __attribute__((ext_vector_type(4)));

struct EncParams {
    const float* X;      // (B, L, 960)
    const int*   mask;   // (B, L) contiguous prefix
    const float* A;      // (L, 16)
    const float* Bc;     // (960, 32)
    const float* Hc;     // (512, dmod)
    const float* W1; const float* b1; const float* gam; const float* beta;
    const float* W2; const float* b2;
    const float* Xclamp; // last valid f32x4 start in X buffer
    int L, dmod, ooff;
};

// =====================================================================
// K0: zero the work-queue counter (ws is poisoned 0xAA by harness).
// =====================================================================
__global__ void zero_kernel(int* __restrict__ q)
{
    if (threadIdx.x == 0) *q = 0;
}

// =====================================================================
// K1: persistent fused per-batch encoder with ASYNC LDS-staged stream.
// Grid 256 x 512 thr, ~88.5 KB LDS -> 1 block/CU (in-flight bytes now
// come from the global_load_lds queue, not wave count).
// Stream: X rows staged in 8-row (30 KB) double-buffered LDS chunks via
//   global_load_lds dwordx4 (4 instr/wave/chunk, flat contiguous copy),
//   counted s_waitcnt vmcnt(4) + raw s_barrier (+ sched_barrier fences)
//   -> ~30 KB/CU in flight -> HBM-bound (r7/r9 reg-staging held only
//   16-32 B/lane -> latency-serialized at ~2-5 TB/s).
// A staged once per item in LDS, rows>=len zeroed + CR pad rows (chunk
//   loop runs all 8 rows unguarded; garbage X rows hit zero A). FMA:
//   2 row-groups x 240 lanes x f32x4 from LDS (conflict-free b128).
// Vs OVERLAYS the dead Xs buffers after the stream (union saves 61 KB).
// Tail (U, z, MLP1, MLP2, concat out) = r9 verbatim at 512 threads.
// =====================================================================
__global__ __launch_bounds__(512)
void persist_kernel(EncParams H, EncParams P, int* __restrict__ qcnt,
                    float* __restrict__ out)
{
    const int t = threadIdx.x;
    __shared__ float UXs[2 * CR * Dd];        // 61440 B: Xs dbuf / Vs / zs,hs
    __shared__ float As[(LHh + CR) * RL];     // 25088 B (len-zeroed + pad)
    __shared__ float Ush[RL * RD];            //  2048 B
    __shared__ int   s_item, s_len;

    const int  grp  = t >> 8;                 // row-group 0..1
    const int  w    = t & 255;
    const bool act  = (w < 240);              // 240 lanes x 4 cols = 960
    const int  col  = 4 * w;
    const int  wave = t >> 6;

    for (;;) {
        __syncthreads();                      // protect LDS reuse across items
        if (t == 0) { s_item = atomicAdd(qcnt, 1); s_len = 0; }
        __syncthreads();
        const int item = s_item;
        if (item >= 2 * Bn) return;
        const bool isH = (item < Bn);
        const EncParams E = isH ? H : P;
        const int b = isH ? item : item - Bn;

        // ---- len = popcount of contiguous-prefix mask row ----
        int loc = 0;
        for (int i = t; i < E.L; i += 512) loc += E.mask[(size_t)b * E.L + i];
        if (loc) atomicAdd(&s_len, loc);
        __syncthreads();
        const int len = __builtin_amdgcn_readfirstlane(s_len);

        // ---- stage A into LDS (rows >= len zeroed, incl. CR pad rows) ----
        for (int i = t; i < (E.L + CR) * 4; i += 512) {
            const int row = i >> 2, q4 = (i & 3) * 4;
            f32x4 av = {0.f, 0.f, 0.f, 0.f};
            if (row < len) av = *(const f32x4*)(E.A + (size_t)row * RL + q4);
            *(f32x4*)&As[row * RL + q4] = av;
        }
        __syncthreads();   // As visible to all waves; drains all counters

        // ---- stream phase: V = A^T Xm, async double-buffered staging ----
        float v[RL][4];
        #pragma unroll
        for (int p = 0; p < RL; ++p)
            { v[p][0] = 0.f; v[p][1] = 0.f; v[p][2] = 0.f; v[p][3] = 0.f; }

        const float* Xb  = E.X + (size_t)b * E.L * Dd;
        const int    nch = (len + CR - 1) / CR;   // >= 1 (len >= 1)

        auto stage = [&](int chunk, int buf) {
            const float* cbase = Xb + (size_t)chunk * CR * Dd;
            #pragma unroll
            for (int i = 0; i < 4; ++i) {
                int slot = wave * 4 + i;
                if (slot >= SLOTS) slot -= 2;     // 30,31 dup 28,29 (same data)
                const float* src = cbase + slot * 256 + (t & 63) * 4;
                if (src > E.Xclamp) src = E.Xclamp;   // end-of-buffer clamp
                __builtin_amdgcn_global_load_lds(
                    (const __attribute__((address_space(1))) void*)src,
                    (__attribute__((address_space(3))) void*)
                        &UXs[buf * CR * Dd + slot * 256],
                    16, 0, 0);
            }
        };

        stage(0, 0);
        for (int k = 0; k < nch; ++k) {
            const int cb = k & 1;
            if (k + 1 < nch) {
                stage(k + 1, cb ^ 1);             // 4 more in flight/wave
                asm volatile("s_waitcnt vmcnt(4)" ::: "memory");  // chunk k done
            } else {
                asm volatile("s_waitcnt vmcnt(0)" ::: "memory");
            }
            __builtin_amdgcn_s_barrier();         // all waves' chunk-k landed
            __builtin_amdgcn_sched_barrier(0);
            if (act) {
                const float* Xc = &UXs[cb * CR * Dd];
                const int c0 = k * CR;
                #pragma unroll
                for (int rr = grp; rr < CR; rr += 2) {
                    f32x4 x = *(const f32x4*)&Xc[rr * Dd + col];
                    const float* ar = &As[(c0 + rr) * RL];
                    float a[RL];
                    *(f32x4*)&a[0]  = *(const f32x4*)(ar + 0);
                    *(f32x4*)&a[4]  = *(const f32x4*)(ar + 4);
                    *(f32x4*)&a[8]  = *(const f32x4*)(ar + 8);
                    *(f32x4*)&a[12] = *(const f32x4*)(ar + 12);
                    #pragma unroll
                    for (int p = 0; p < RL; ++p) {
                        v[p][0] = fmaf(a[p], x[0], v[p][0]);
                        v[p][1] = fmaf(a[p], x[1], v[p][1]);
                        v[p][2] = fmaf(a[p], x[2], v[p][2]);
                        v[p][3] = fmaf(a[p], x[3], v[p][3]);
                    }
                }
            }
            __builtin_amdgcn_sched_barrier(0);
            __builtin_amdgcn_s_barrier();         // readers done before overwrite
        }

        // ---- combine row-groups into Vs (overlays dead Xs buffers) ----
        float* Vs = &UXs[0];                      // [16][960]
        if (grp == 0 && act) {
            #pragma unroll
            for (int p = 0; p < RL; ++p)
                *(f32x4*)&Vs[p * Dd + col] = *(f32x4*)&v[p][0];
        }
        __syncthreads();
        if (grp == 1 && act) {
            #pragma unroll
            for (int p = 0; p < RL; ++p) {
                f32x4 c = *(const f32x4*)&Vs[p * Dd + col];
                c += *(f32x4*)&v[p][0];
                *(f32x4*)&Vs[p * Dd + col] = c;
            }
        }
        __syncthreads();

        // ---- U phase: thread t = (p,r) computes one U entry ----
        {
            const int p = t >> 5, r = t & 31;
            float u0 = 0.f, u1 = 0.f;
            for (int dd = 0; dd < Dd; dd += 8) {
                f32x4 va = *(const f32x4*)&Vs[p * Dd + dd];
                f32x4 vb = *(const f32x4*)&Vs[p * Dd + dd + 4];
                #pragma unroll
                for (int q = 0; q < 4; ++q) {
                    u0 = fmaf(va[q], E.Bc[(size_t)(dd + q) * RD + r],     u0);
                    u1 = fmaf(vb[q], E.Bc[(size_t)(dd + 4 + q) * RD + r], u1);
                }
            }
            Ush[t] = u0 + u1;                     // t == p*32 + r
        }
        __syncthreads();

        // ---- z phase: z = vec(U) @ Hc (zs/hs reuse dead Vs space) ----
        float* zs = &UXs[0];
        float* hs = zs + 512;
        for (int j = t; j < E.dmod; j += 512) {
            float a0 = 0.f, a1 = 0.f, a2 = 0.f, a3 = 0.f;
            #pragma unroll 4
            for (int i = 0; i < RL * RD; i += 4) {
                a0 = fmaf(Ush[i],     E.Hc[(size_t)i * E.dmod + j],       a0);
                a1 = fmaf(Ush[i + 1], E.Hc[(size_t)(i + 1) * E.dmod + j], a1);
                a2 = fmaf(Ush[i + 2], E.Hc[(size_t)(i + 2) * E.dmod + j], a2);
                a3 = fmaf(Ush[i + 3], E.Hc[(size_t)(i + 3) * E.dmod + j], a3);
            }
            zs[j] = (a0 + a1) + (a2 + a3);
        }
        __syncthreads();

        // ---- MLP layer 1 + BN + ReLU ----
        const float bscale = rsqrtf(1.f + 1e-5f);
        const int K = E.dmod;
        for (int c = t; c < K; c += 512) {
            float a0 = E.b1[c], a1 = 0.f;
            #pragma unroll 4
            for (int k = 0; k < K; k += 2) {      // K even (358/154)
                a0 = fmaf(zs[k],     E.W1[(size_t)k * K + c],       a0);
                a1 = fmaf(zs[k + 1], E.W1[(size_t)(k + 1) * K + c], a1);
            }
            float acc = a0 + a1;
            acc = fmaf(acc, E.gam[c] * bscale, E.beta[c]);
            hs[c] = fmaxf(acc, 0.f);
        }
        __syncthreads();

        // ---- MLP layer 2 + concat store ----
        for (int c = t; c < K; c += 512) {
            float a0 = E.b2[c], a1 = 0.f;
            #pragma unroll 4
            for (int k = 0; k < K; k += 2) {
                a0 = fmaf(hs[k],     E.W2[(size_t)k * K + c],       a0);
                a1 = fmaf(hs[k + 1], E.W2[(size_t)(k + 1) * K + c], a1);
            }
            out[(size_t)b * (DP + DH) + E.ooff + c] = a0 + a1;
        }
        // loop: top-of-loop __syncthreads protects UXs/As/Ush reuse
    }
}

// =====================================================================
extern "C" void kernel_launch(void* const* d_in, const int* in_sizes, int n_in,
                              void* d_out, int out_size, void* d_ws, size_t ws_size,
                              hipStream_t stream)
{
    EncParams P, H;
    P.X    = (const float*)d_in[0];
    H.X    = (const float*)d_in[1];
    P.mask = (const int*)  d_in[2];
    H.mask = (const int*)  d_in[3];
    P.Bc   = (const float*)d_in[4];
    P.A    = (const float*)d_in[5];
    P.Hc   = (const float*)d_in[6];
    P.W1   = (const float*)d_in[7];
    P.b1   = (const float*)d_in[8];
    P.gam  = (const float*)d_in[9];
    P.beta = (const float*)d_in[10];
    P.W2   = (const float*)d_in[11];
    P.b2   = (const float*)d_in[12];
    H.Bc   = (const float*)d_in[13];
    H.A    = (const float*)d_in[14];
    H.Hc   = (const float*)d_in[15];
    H.W1   = (const float*)d_in[16];
    H.b1   = (const float*)d_in[17];
    H.gam  = (const float*)d_in[18];
    H.beta = (const float*)d_in[19];
    H.W2   = (const float*)d_in[20];
    H.b2   = (const float*)d_in[21];
    P.L = LPp;  P.dmod = DP;  P.ooff = 0;
    H.L = LHh;  H.dmod = DH;  H.ooff = DP;
    P.Xclamp = P.X + (size_t)in_sizes[0] - 4;
    H.Xclamp = H.X + (size_t)in_sizes[1] - 4;

    float* outp = (float*)d_out;
    int*   qcnt = (int*)d_ws;

    zero_kernel<<<dim3(1), dim3(64), 0, stream>>>(qcnt);
    persist_kernel<<<dim3(256), dim3(512), 0, stream>>>(H, P, qcnt, outp);
}

// Round 14
// 271.316 us; speedup vs baseline: 1.0210x; 1.0210x over previous
//
#include <hip/hip_runtime.h>
#include <cstddef>

// Problem constants
constexpr int Bn  = 512;
constexpr int Dd  = 960;
constexpr int RL  = 16;
constexpr int RD  = 32;
constexpr int LPp = 16;
constexpr int LHh = 384;
constexpr int DP  = 358;
constexpr int DH  = 154;
constexpr int CR  = 8;                     // rows per staged X chunk
constexpr int SLOTS = (CR * Dd) / 256;     // 30 slots of 1024 B (256 f32)

typedef float f32x4 __attribute__((ext_vector_type(4)));

struct EncParams {
    const float* X;      // (B, L, 960)
    const int*   mask;   // (B, L) contiguous prefix
    const float* A;      // (L, 16)
    const float* Bc;     // (960, 32)
    const float* Hc;     // (512, dmod)
    const float* W1; const float* b1; const float* gam; const float* beta;
    const float* W2; const float* b2;
    const float* Xclamp; // last valid f32x4 start in X buffer
    int L, dmod, ooff;
};

// =====================================================================
// K0: zero the work-queue counter (ws is poisoned 0xAA by harness).
// =====================================================================
__global__ void zero_kernel(int* __restrict__ q)
{
    if (threadIdx.x == 0) *q = 0;
}

// =====================================================================
// K1: persistent fused per-batch encoder with ASYNC LDS-staged stream.
// Grid 256 x 512 thr, ~88.5 KB LDS -> 1 block/CU (in-flight bytes now
// come from the global_load_lds queue, not wave count).
// Stream: X rows staged in 8-row (30 KB) double-buffered LDS chunks via
//   global_load_lds dwordx4 (4 instr/wave/chunk, flat contiguous copy),
//   counted s_waitcnt vmcnt(4) + raw s_barrier (+ sched_barrier fences)
//   -> ~30 KB/CU in flight -> HBM-bound (r7/r9 reg-staging held only
//   16-32 B/lane -> latency-serialized at ~2-5 TB/s).
// A staged once per item in LDS, rows>=len zeroed + CR pad rows (chunk
//   loop runs all 8 rows unguarded; garbage X rows hit zero A). FMA:
//   2 row-groups x 240 lanes x f32x4 from LDS (conflict-free b128).
// Vs OVERLAYS the dead Xs buffers after the stream (union saves 61 KB).
// Tail (U, z, MLP1, MLP2, concat out) = r9 verbatim at 512 threads.
// =====================================================================
__global__ __launch_bounds__(512)
void persist_kernel(EncParams H, EncParams P, int* __restrict__ qcnt,
                    float* __restrict__ out)
{
    const int t = threadIdx.x;
    __shared__ float UXs[2 * CR * Dd];        // 61440 B: Xs dbuf / Vs / zs,hs
    __shared__ float As[(LHh + CR) * RL];     // 25088 B (len-zeroed + pad)
    __shared__ float Ush[RL * RD];            //  2048 B
    __shared__ int   s_item, s_len;

    const int  grp  = t >> 8;                 // row-group 0..1
    const int  w    = t & 255;
    const bool act  = (w < 240);              // 240 lanes x 4 cols = 960
    const int  col  = 4 * w;
    const int  wave = t >> 6;

    for (;;) {
        __syncthreads();                      // protect LDS reuse across items
        if (t == 0) { s_item = atomicAdd(qcnt, 1); s_len = 0; }
        __syncthreads();
        const int item = s_item;
        if (item >= 2 * Bn) return;
        const bool isH = (item < Bn);
        const EncParams E = isH ? H : P;
        const int b = isH ? item : item - Bn;

        // ---- len = popcount of contiguous-prefix mask row ----
        int loc = 0;
        for (int i = t; i < E.L; i += 512) loc += E.mask[(size_t)b * E.L + i];
        if (loc) atomicAdd(&s_len, loc);
        __syncthreads();
        const int len = __builtin_amdgcn_readfirstlane(s_len);

        // ---- stage A into LDS (rows >= len zeroed, incl. CR pad rows) ----
        for (int i = t; i < (E.L + CR) * 4; i += 512) {
            const int row = i >> 2, q4 = (i & 3) * 4;
            f32x4 av = {0.f, 0.f, 0.f, 0.f};
            if (row < len) av = *(const f32x4*)(E.A + (size_t)row * RL + q4);
            *(f32x4*)&As[row * RL + q4] = av;
        }
        __syncthreads();   // As visible to all waves; drains all counters

        // ---- stream phase: V = A^T Xm, async double-buffered staging ----
        float v[RL][4];
        #pragma unroll
        for (int p = 0; p < RL; ++p)
            { v[p][0] = 0.f; v[p][1] = 0.f; v[p][2] = 0.f; v[p][3] = 0.f; }

        const float* Xb  = E.X + (size_t)b * E.L * Dd;
        const int    nch = (len + CR - 1) / CR;   // >= 1 (len >= 1)

        auto stage = [&](int chunk, int buf) {
            const float* cbase = Xb + (size_t)chunk * CR * Dd;
            #pragma unroll
            for (int i = 0; i < 4; ++i) {
                int slot = wave * 4 + i;
                if (slot >= SLOTS) slot -= 2;     // 30,31 dup 28,29 (same data)
                const float* src = cbase + slot * 256 + (t & 63) * 4;
                if (src > E.Xclamp) src = E.Xclamp;   // end-of-buffer clamp
                __builtin_amdgcn_global_load_lds(
                    (const __attribute__((address_space(1))) void*)src,
                    (__attribute__((address_space(3))) void*)
                        &UXs[buf * CR * Dd + slot * 256],
                    16, 0, 0);
            }
        };

        stage(0, 0);
        for (int k = 0; k < nch; ++k) {
            const int cb = k & 1;
            if (k + 1 < nch) {
                stage(k + 1, cb ^ 1);             // 4 more in flight/wave
                asm volatile("s_waitcnt vmcnt(4)" ::: "memory");  // chunk k done
            } else {
                asm volatile("s_waitcnt vmcnt(0)" ::: "memory");
            }
            __builtin_amdgcn_s_barrier();         // all waves' chunk-k landed
            __builtin_amdgcn_sched_barrier(0);
            if (act) {
                const float* Xc = &UXs[cb * CR * Dd];
                const int c0 = k * CR;
                #pragma unroll
                for (int rr = grp; rr < CR; rr += 2) {
                    f32x4 x = *(const f32x4*)&Xc[rr * Dd + col];
                    const float* ar = &As[(c0 + rr) * RL];
                    float a[RL];
                    *(f32x4*)&a[0]  = *(const f32x4*)(ar + 0);
                    *(f32x4*)&a[4]  = *(const f32x4*)(ar + 4);
                    *(f32x4*)&a[8]  = *(const f32x4*)(ar + 8);
                    *(f32x4*)&a[12] = *(const f32x4*)(ar + 12);
                    #pragma unroll
                    for (int p = 0; p < RL; ++p) {
                        v[p][0] = fmaf(a[p], x[0], v[p][0]);
                        v[p][1] = fmaf(a[p], x[1], v[p][1]);
                        v[p][2] = fmaf(a[p], x[2], v[p][2]);
                        v[p][3] = fmaf(a[p], x[3], v[p][3]);
                    }
                }
            }
            __builtin_amdgcn_sched_barrier(0);
            __builtin_amdgcn_s_barrier();         // readers done before overwrite
        }

        // ---- combine row-groups into Vs (overlays dead Xs buffers) ----
        float* Vs = &UXs[0];                      // [16][960]
        if (grp == 0 && act) {
            #pragma unroll
            for (int p = 0; p < RL; ++p)
                *(f32x4*)&Vs[p * Dd + col] = *(f32x4*)&v[p][0];
        }
        __syncthreads();
        if (grp == 1 && act) {
            #pragma unroll
            for (int p = 0; p < RL; ++p) {
                f32x4 c = *(const f32x4*)&Vs[p * Dd + col];
                c += *(f32x4*)&v[p][0];
                *(f32x4*)&Vs[p * Dd + col] = c;
            }
        }
        __syncthreads();

        // ---- U phase: thread t = (p,r) computes one U entry ----
        {
            const int p = t >> 5, r = t & 31;
            float u0 = 0.f, u1 = 0.f;
            for (int dd = 0; dd < Dd; dd += 8) {
                f32x4 va = *(const f32x4*)&Vs[p * Dd + dd];
                f32x4 vb = *(const f32x4*)&Vs[p * Dd + dd + 4];
                #pragma unroll
                for (int q = 0; q < 4; ++q) {
                    u0 = fmaf(va[q], E.Bc[(size_t)(dd + q) * RD + r],     u0);
                    u1 = fmaf(vb[q], E.Bc[(size_t)(dd + 4 + q) * RD + r], u1);
                }
            }
            Ush[t] = u0 + u1;                     // t == p*32 + r
        }
        __syncthreads();

        // ---- z phase: z = vec(U) @ Hc (zs/hs reuse dead Vs space) ----
        float* zs = &UXs[0];
        float* hs = zs + 512;
        for (int j = t; j < E.dmod; j += 512) {
            float a0 = 0.f, a1 = 0.f, a2 = 0.f, a3 = 0.f;
            #pragma unroll 4
            for (int i = 0; i < RL * RD; i += 4) {
                a0 = fmaf(Ush[i],     E.Hc[(size_t)i * E.dmod + j],       a0);
                a1 = fmaf(Ush[i + 1], E.Hc[(size_t)(i + 1) * E.dmod + j], a1);
                a2 = fmaf(Ush[i + 2], E.Hc[(size_t)(i + 2) * E.dmod + j], a2);
                a3 = fmaf(Ush[i + 3], E.Hc[(size_t)(i + 3) * E.dmod + j], a3);
            }
            zs[j] = (a0 + a1) + (a2 + a3);
        }
        __syncthreads();

        // ---- MLP layer 1 + BN + ReLU ----
        const float bscale = rsqrtf(1.f + 1e-5f);
        const int K = E.dmod;
        for (int c = t; c < K; c += 512) {
            float a0 = E.b1[c], a1 = 0.f;
            #pragma unroll 4
            for (int k = 0; k < K; k += 2) {      // K even (358/154)
                a0 = fmaf(zs[k],     E.W1[(size_t)k * K + c],       a0);
                a1 = fmaf(zs[k + 1], E.W1[(size_t)(k + 1) * K + c], a1);
            }
            float acc = a0 + a1;
            acc = fmaf(acc, E.gam[c] * bscale, E.beta[c]);
            hs[c] = fmaxf(acc, 0.f);
        }
        __syncthreads();

        // ---- MLP layer 2 + concat store ----
        for (int c = t; c < K; c += 512) {
            float a0 = E.b2[c], a1 = 0.f;
            #pragma unroll 4
            for (int k = 0; k < K; k += 2) {
                a0 = fmaf(hs[k],     E.W2[(size_t)k * K + c],       a0);
                a1 = fmaf(hs[k + 1], E.W2[(size_t)(k + 1) * K + c], a1);
            }
            out[(size_t)b * (DP + DH) + E.ooff + c] = a0 + a1;
        }
        // loop: top-of-loop __syncthreads protects UXs/As/Ush reuse
    }
}

// =====================================================================
extern "C" void kernel_launch(void* const* d_in, const int* in_sizes, int n_in,
                              void* d_out, int out_size, void* d_ws, size_t ws_size,
                              hipStream_t stream)
{
    EncParams P, H;
    P.X    = (const float*)d_in[0];
    H.X    = (const float*)d_in[1];
    P.mask = (const int*)  d_in[2];
    H.mask = (const int*)  d_in[3];
    P.Bc   = (const float*)d_in[4];
    P.A    = (const float*)d_in[5];
    P.Hc   = (const float*)d_in[6];
    P.W1   = (const float*)d_in[7];
    P.b1   = (const float*)d_in[8];
    P.gam  = (const float*)d_in[9];
    P.beta = (const float*)d_in[10];
    P.W2   = (const float*)d_in[11];
    P.b2   = (const float*)d_in[12];
    H.Bc   = (const float*)d_in[13];
    H.A    = (const float*)d_in[14];
    H.Hc   = (const float*)d_in[15];
    H.W1   = (const float*)d_in[16];
    H.b1   = (const float*)d_in[17];
    H.gam  = (const float*)d_in[18];
    H.beta = (const float*)d_in[19];
    H.W2   = (const float*)d_in[20];
    H.b2   = (const float*)d_in[21];
    P.L = LPp;  P.dmod = DP;  P.ooff = 0;
    H.L = LHh;  H.dmod = DH;  H.ooff = DP;
    P.Xclamp = P.X + (size_t)in_sizes[0] - 4;
    H.Xclamp = H.X + (size_t)in_sizes[1] - 4;

    float* outp = (float*)d_out;
    int*   qcnt = (int*)d_ws;

    zero_kernel<<<dim3(1), dim3(64), 0, stream>>>(qcnt);
    persist_kernel<<<dim3(256), dim3(512), 0, stream>>>(H, P, qcnt, outp);
}

// Round 15
// 267.382 us; speedup vs baseline: 1.0360x; 1.0147x over previous
//
#include <hip/hip_runtime.h>
#include <cstddef>

// Problem constants
constexpr int Bn  = 512;
constexpr int Dd  = 960;
constexpr int RL  = 16;
constexpr int RD  = 32;
constexpr int LPp = 16;
constexpr int LHh = 384;
constexpr int DP  = 358;
constexpr int DH  = 154;
constexpr int CR  = 8;                     // rows per staged X chunk
constexpr int SLOTS = (CR * Dd) / 256;     // 30 slots of 1024 B (256 f32)

typedef float f32x4 __attribute__((ext_vector_type(4)));

struct EncParams {
    const float* X;      // (B, L, 960)
    const int*   mask;   // (B, L) contiguous prefix
    const float* A;      // (L, 16)
    const float* Bc;     // (960, 32)
    const float* Hc;     // (512, dmod)
    const float* W1; const float* b1; const float* gam; const float* beta;
    const float* W2; const float* b2;
    const float* Xclamp; // last valid f32x4 start in X buffer
    int L, dmod, ooff;
};

// =====================================================================
// K0: zero the work-queue counter (ws is poisoned 0xAA by harness).
// =====================================================================
__global__ void zero_kernel(int* __restrict__ q)
{
    if (threadIdx.x == 0) *q = 0;
}

// =====================================================================
// K1: persistent fused per-batch encoder with ASYNC LDS-staged stream.
// Grid 256 x 512 thr, ~88.5 KB LDS -> 1 block/CU (in-flight bytes now
// come from the global_load_lds queue, not wave count).
// Stream: X rows staged in 8-row (30 KB) double-buffered LDS chunks via
//   global_load_lds dwordx4 (4 instr/wave/chunk, flat contiguous copy),
//   counted s_waitcnt vmcnt(4) + raw s_barrier (+ sched_barrier fences)
//   -> ~30 KB/CU in flight -> HBM-bound (r7/r9 reg-staging held only
//   16-32 B/lane -> latency-serialized at ~2-5 TB/s).
// A staged once per item in LDS, rows>=len zeroed + CR pad rows (chunk
//   loop runs all 8 rows unguarded; garbage X rows hit zero A). FMA:
//   2 row-groups x 240 lanes x f32x4 from LDS (conflict-free b128).
// Vs OVERLAYS the dead Xs buffers after the stream (union saves 61 KB).
// Tail (U, z, MLP1, MLP2, concat out) = r9 verbatim at 512 threads.
// =====================================================================
__global__ __launch_bounds__(512)
void persist_kernel(EncParams H, EncParams P, int* __restrict__ qcnt,
                    float* __restrict__ out)
{
    const int t = threadIdx.x;
    __shared__ float UXs[2 * CR * Dd];        // 61440 B: Xs dbuf / Vs / zs,hs
    __shared__ float As[(LHh + CR) * RL];     // 25088 B (len-zeroed + pad)
    __shared__ float Ush[RL * RD];            //  2048 B
    __shared__ int   s_item, s_len;

    const int  grp  = t >> 8;                 // row-group 0..1
    const int  w    = t & 255;
    const bool act  = (w < 240);              // 240 lanes x 4 cols = 960
    const int  col  = 4 * w;
    const int  wave = t >> 6;

    for (;;) {
        __syncthreads();                      // protect LDS reuse across items
        if (t == 0) { s_item = atomicAdd(qcnt, 1); s_len = 0; }
        __syncthreads();
        const int item = s_item;
        if (item >= 2 * Bn) return;
        const bool isH = (item < Bn);
        const EncParams E = isH ? H : P;
        const int b = isH ? item : item - Bn;

        // ---- len = popcount of contiguous-prefix mask row ----
        int loc = 0;
        for (int i = t; i < E.L; i += 512) loc += E.mask[(size_t)b * E.L + i];
        if (loc) atomicAdd(&s_len, loc);
        __syncthreads();
        const int len = __builtin_amdgcn_readfirstlane(s_len);

        // ---- stage A into LDS (rows >= len zeroed, incl. CR pad rows) ----
        for (int i = t; i < (E.L + CR) * 4; i += 512) {
            const int row = i >> 2, q4 = (i & 3) * 4;
            f32x4 av = {0.f, 0.f, 0.f, 0.f};
            if (row < len) av = *(const f32x4*)(E.A + (size_t)row * RL + q4);
            *(f32x4*)&As[row * RL + q4] = av;
        }
        __syncthreads();   // As visible to all waves; drains all counters

        // ---- stream phase: V = A^T Xm, async double-buffered staging ----
        float v[RL][4];
        #pragma unroll
        for (int p = 0; p < RL; ++p)
            { v[p][0] = 0.f; v[p][1] = 0.f; v[p][2] = 0.f; v[p][3] = 0.f; }

        const float* Xb  = E.X + (size_t)b * E.L * Dd;
        const int    nch = (len + CR - 1) / CR;   // >= 1 (len >= 1)

        auto stage = [&](int chunk, int buf) {
            const float* cbase = Xb + (size_t)chunk * CR * Dd;
            #pragma unroll
            for (int i = 0; i < 4; ++i) {
                int slot = wave * 4 + i;
                if (slot >= SLOTS) slot -= 2;     // 30,31 dup 28,29 (same data)
                const float* src = cbase + slot * 256 + (t & 63) * 4;
                if (src > E.Xclamp) src = E.Xclamp;   // end-of-buffer clamp
                __builtin_amdgcn_global_load_lds(
                    (const __attribute__((address_space(1))) void*)src,
                    (__attribute__((address_space(3))) void*)
                        &UXs[buf * CR * Dd + slot * 256],
                    16, 0, 0);
            }
        };

        stage(0, 0);
        for (int k = 0; k < nch; ++k) {
            const int cb = k & 1;
            if (k + 1 < nch) {
                stage(k + 1, cb ^ 1);             // 4 more in flight/wave
                asm volatile("s_waitcnt vmcnt(4)" ::: "memory");  // chunk k done
            } else {
                asm volatile("s_waitcnt vmcnt(0)" ::: "memory");
            }
            __builtin_amdgcn_s_barrier();         // all waves' chunk-k landed
            __builtin_amdgcn_sched_barrier(0);
            if (act) {
                const float* Xc = &UXs[cb * CR * Dd];
                const int c0 = k * CR;
                #pragma unroll
                for (int rr = grp; rr < CR; rr += 2) {
                    f32x4 x = *(const f32x4*)&Xc[rr * Dd + col];
                    const float* ar = &As[(c0 + rr) * RL];
                    float a[RL];
                    *(f32x4*)&a[0]  = *(const f32x4*)(ar + 0);
                    *(f32x4*)&a[4]  = *(const f32x4*)(ar + 4);
                    *(f32x4*)&a[8]  = *(const f32x4*)(ar + 8);
                    *(f32x4*)&a[12] = *(const f32x4*)(ar + 12);
                    #pragma unroll
                    for (int p = 0; p < RL; ++p) {
                        v[p][0] = fmaf(a[p], x[0], v[p][0]);
                        v[p][1] = fmaf(a[p], x[1], v[p][1]);
                        v[p][2] = fmaf(a[p], x[2], v[p][2]);
                        v[p][3] = fmaf(a[p], x[3], v[p][3]);
                    }
                }
            }
            __builtin_amdgcn_sched_barrier(0);
            __builtin_amdgcn_s_barrier();         // readers done before overwrite
        }

        // ---- combine row-groups into Vs (overlays dead Xs buffers) ----
        float* Vs = &UXs[0];                      // [16][960]
        if (grp == 0 && act) {
            #pragma unroll
            for (int p = 0; p < RL; ++p)
                *(f32x4*)&Vs[p * Dd + col] = *(f32x4*)&v[p][0];
        }
        __syncthreads();
        if (grp == 1 && act) {
            #pragma unroll
            for (int p = 0; p < RL; ++p) {
                f32x4 c = *(const f32x4*)&Vs[p * Dd + col];
                c += *(f32x4*)&v[p][0];
                *(f32x4*)&Vs[p * Dd + col] = c;
            }
        }
        __syncthreads();

        // ---- U phase: thread t = (p,r) computes one U entry ----
        {
            const int p = t >> 5, r = t & 31;
            float u0 = 0.f, u1 = 0.f;
            for (int dd = 0; dd < Dd; dd += 8) {
                f32x4 va = *(const f32x4*)&Vs[p * Dd + dd];
                f32x4 vb = *(const f32x4*)&Vs[p * Dd + dd + 4];
                #pragma unroll
                for (int q = 0; q < 4; ++q) {
                    u0 = fmaf(va[q], E.Bc[(size_t)(dd + q) * RD + r],     u0);
                    u1 = fmaf(vb[q], E.Bc[(size_t)(dd + 4 + q) * RD + r], u1);
                }
            }
            Ush[t] = u0 + u1;                     // t == p*32 + r
        }
        __syncthreads();

        // ---- z phase: z = vec(U) @ Hc (zs/hs reuse dead Vs space) ----
        float* zs = &UXs[0];
        float* hs = zs + 512;
        for (int j = t; j < E.dmod; j += 512) {
            float a0 = 0.f, a1 = 0.f, a2 = 0.f, a3 = 0.f;
            #pragma unroll 4
            for (int i = 0; i < RL * RD; i += 4) {
                a0 = fmaf(Ush[i],     E.Hc[(size_t)i * E.dmod + j],       a0);
                a1 = fmaf(Ush[i + 1], E.Hc[(size_t)(i + 1) * E.dmod + j], a1);
                a2 = fmaf(Ush[i + 2], E.Hc[(size_t)(i + 2) * E.dmod + j], a2);
                a3 = fmaf(Ush[i + 3], E.Hc[(size_t)(i + 3) * E.dmod + j], a3);
            }
            zs[j] = (a0 + a1) + (a2 + a3);
        }
        __syncthreads();

        // ---- MLP layer 1 + BN + ReLU ----
        const float bscale = rsqrtf(1.f + 1e-5f);
        const int K = E.dmod;
        for (int c = t; c < K; c += 512) {
            float a0 = E.b1[c], a1 = 0.f;
            #pragma unroll 4
            for (int k = 0; k < K; k += 2) {      // K even (358/154)
                a0 = fmaf(zs[k],     E.W1[(size_t)k * K + c],       a0);
                a1 = fmaf(zs[k + 1], E.W1[(size_t)(k + 1) * K + c], a1);
            }
            float acc = a0 + a1;
            acc = fmaf(acc, E.gam[c] * bscale, E.beta[c]);
            hs[c] = fmaxf(acc, 0.f);
        }
        __syncthreads();

        // ---- MLP layer 2 + concat store ----
        for (int c = t; c < K; c += 512) {
            float a0 = E.b2[c], a1 = 0.f;
            #pragma unroll 4
            for (int k = 0; k < K; k += 2) {
                a0 = fmaf(hs[k],     E.W2[(size_t)k * K + c],       a0);
                a1 = fmaf(hs[k + 1], E.W2[(size_t)(k + 1) * K + c], a1);
            }
            out[(size_t)b * (DP + DH) + E.ooff + c] = a0 + a1;
        }
        // loop: top-of-loop __syncthreads protects UXs/As/Ush reuse
    }
}

// =====================================================================
extern "C" void kernel_launch(void* const* d_in, const int* in_sizes, int n_in,
                              void* d_out, int out_size, void* d_ws, size_t ws_size,
                              hipStream_t stream)
{
    EncParams P, H;
    P.X    = (const float*)d_in[0];
    H.X    = (const float*)d_in[1];
    P.mask = (const int*)  d_in[2];
    H.mask = (const int*)  d_in[3];
    P.Bc   = (const float*)d_in[4];
    P.A    = (const float*)d_in[5];
    P.Hc   = (const float*)d_in[6];
    P.W1   = (const float*)d_in[7];
    P.b1   = (const float*)d_in[8];
    P.gam  = (const float*)d_in[9];
    P.beta = (const float*)d_in[10];
    P.W2   = (const float*)d_in[11];
    P.b2   = (const float*)d_in[12];
    H.Bc   = (const float*)d_in[13];
    H.A    = (const float*)d_in[14];
    H.Hc   = (const float*)d_in[15];
    H.W1   = (const float*)d_in[16];
    H.b1   = (const float*)d_in[17];
    H.gam  = (const float*)d_in[18];
    H.beta = (const float*)d_in[19];
    H.W2   = (const float*)d_in[20];
    H.b2   = (const float*)d_in[21];
    P.L = LPp;  P.dmod = DP;  P.ooff = 0;
    H.L = LHh;  H.dmod = DH;  H.ooff = DP;
    P.Xclamp = P.X + (size_t)in_sizes[0] - 4;
    H.Xclamp = H.X + (size_t)in_sizes[1] - 4;

    float* outp = (float*)d_out;
    int*   qcnt = (int*)d_ws;

    zero_kernel<<<dim3(1), dim3(64), 0, stream>>>(qcnt);
    persist_kernel<<<dim3(256), dim3(512), 0, stream>>>(H, P, qcnt, outp);
}